// Round 4
// baseline (148.130 us; speedup 1.0000x reference)
//
#include <hip/hip_runtime.h>
#include <math.h>

#pragma clang fp contract(off)

#define BS 16
#define NA 8400
#define NG 128
#define NC 80
#define KTOP 13
#define QCAP 1024   // per-column in-box queue capacity (worst case ~500)

// ---- workspace layout (bytes) ----
#define OFF_BITS   0                                    // BS*NA*4 u32 = 2,150,400
#define OFF_SELCNT ((size_t)BS * NA * 16)               // BS*NA u32   =   537,600
#define OFF_FLAG   (OFF_SELCNT + (size_t)BS * NA * 4)   // 256 bytes
#define OFF_BESTK  (OFF_FLAG + 256)                     // BS*NA u64   = 1,075,200

// ---- output layout (float elements) ----
#define OUT_CLS    0
#define OUT_BBOX   (BS * NA)
#define OUT_SCORES (OUT_BBOX + BS * NA * 4)
#define OUT_MASK   (OUT_SCORES + BS * NA * NC)
#define OUT_NORM   (OUT_MASK + BS * NA)

__device__ __forceinline__ float dev_ciou(float px1, float py1, float px2, float py2,
                                          float gx1, float gy1, float gx2, float gy2) {
    const float eps = 1e-7f;
    float iw = fminf(px2, gx2) - fmaxf(px1, gx1); iw = fmaxf(iw, 0.0f);
    float ih = fminf(py2, gy2) - fmaxf(py1, gy1); ih = fmaxf(ih, 0.0f);
    float inter = iw * ih;
    float w1 = px2 - px1;
    float h1 = (py2 - py1) + eps;
    float w2 = gx2 - gx1;
    float h2 = (gy2 - gy1) + eps;
    float uni = ((w1 * h1 + w2 * h2) - inter) + eps;
    float iou = inter / uni;
    float cw = fmaxf(px2, gx2) - fminf(px1, gx1);
    float ch = fmaxf(py2, gy2) - fminf(py1, gy1);
    float c2 = (cw * cw + ch * ch) + eps;
    float tx = ((gx1 + gx2) - px1) - px2;
    float ty = ((gy1 + gy2) - py1) - py2;
    float rho2 = (tx * tx + ty * ty) / 4.0f;
    float da = atanf(w2 / h2) - atanf(w1 / h1);
    float v = ((float)(4.0 / (M_PI * M_PI))) * (da * da);
    float alpha = v / ((v - iou) + (float)(1.0 + 1e-7));
    float res = iou - (rho2 / c2 + v * alpha);
    return fmaxf(res, 0.0f);
}

// K0: zero bits/selcnt/flag, seed bestkey = pack(al=0.0f, g=0) = 127
__global__ __launch_bounds__(256) void k_init(
    unsigned int* __restrict__ bits, unsigned int* __restrict__ selcnt,
    int* __restrict__ flag, unsigned long long* __restrict__ bestkey)
{
    int i = blockIdx.x * 256 + threadIdx.x;
    if (i < BS * NA) {
        ((uint4*)bits)[i] = make_uint4(0u, 0u, 0u, 0u);
        selcnt[i] = 0u;
        bestkey[i] = 127ULL;
    }
    if (i == 0) *flag = 0;
}

// K1: fused build+select, one block per (b,g) column.
// Phase 1: cheap in-box scan of 8400 anchors -> LDS queue of anchor ids.
// Phase 2: dense align over the queue; global atomicMax per-anchor best key.
// Phase 3: in-block top-13 (value desc, anchor asc; stop when max <= 1e-9),
//          scatter bits + selcnt + conflict flag.
__global__ __launch_bounds__(256) void k_build_select(
    const float* __restrict__ scores, const float* __restrict__ pboxes,
    const float* __restrict__ anc, const int* __restrict__ glab,
    const float* __restrict__ gboxes, const float* __restrict__ gmask,
    unsigned int* __restrict__ bits, unsigned int* __restrict__ selcnt,
    int* __restrict__ flag, unsigned long long* __restrict__ bestkey)
{
    __shared__ unsigned short s_idx[QCAP];
    __shared__ float s_val[QCAP];
    __shared__ unsigned int s_qn;
    __shared__ unsigned int s_win;
    __shared__ float s_rv[4];
    __shared__ unsigned int s_ra[4];

    int g = blockIdx.x, b = blockIdx.y;
    int col = b * NG + g;
    int tid = threadIdx.x;
    float gm = gmask[col];                 // block-uniform
    float gx1 = gboxes[col * 4 + 0], gy1 = gboxes[col * 4 + 1];
    float gx2 = gboxes[col * 4 + 2], gy2 = gboxes[col * 4 + 3];
    int cls = glab[col];
    if (tid == 0) s_qn = 0;
    __syncthreads();

    // phase 1
    if (gm != 0.0f) {
        for (int a = tid; a < NA; a += 256) {
            float ax = anc[a * 2 + 0], ay = anc[a * 2 + 1];
            float mn = fminf(fminf(ax - gx1, ay - gy1), fminf(gx2 - ax, gy2 - ay));
            if (mn > 1e-9f) {
                unsigned int pos = atomicAdd(&s_qn, 1u);
                if (pos < QCAP) s_idx[pos] = (unsigned short)a;
            }
        }
    }
    __syncthreads();
    int qn = (int)s_qn; if (qn > QCAP) qn = QCAP;

    // phase 2
    for (int i = tid; i < qn; i += 256) {
        int a = (int)s_idx[i];
        size_t t = (size_t)b * NA + a;
        float4 pb = ((const float4*)pboxes)[t];
        float iou = dev_ciou(pb.x, pb.y, pb.z, pb.w, gx1, gy1, gx2, gy2);
        float s = scores[t * NC + cls];
        float al = (s * powf(iou, 6.0f)) * gm;   // same expr as reference path
        s_val[i] = (al > 1e-9f) ? al : -1.0f;    // sentinel: excluded from top-k
        // first-occurrence row argmax: al>=0 -> bits order-monotone; (127-g) low
        // bits make smaller g win ties under max.
        unsigned long long key =
            ((unsigned long long)__float_as_uint(al) << 32) | (unsigned int)(127 - g);
        atomicMax(&bestkey[t], key);
    }
    __syncthreads();

    if (!(gm > 0.0f)) return;   // column excluded from is_in (uniform branch)

    // phase 3: iterative top-13
    int lane = tid & 63, wv = tid >> 6;
    for (int k = 0; k < KTOP; k++) {
        float bv = -1.0f; unsigned int ba = 0xFFFFFFFFu;
        for (int i = tid; i < qn; i += 256) {
            float v = s_val[i]; unsigned int a = s_idx[i];
            if (v > bv || (v == bv && a < ba)) { bv = v; ba = a; }
        }
        for (int off = 1; off < 64; off <<= 1) {
            float ov = __shfl_xor(bv, off);
            unsigned int oa = (unsigned int)__shfl_xor((int)ba, off);
            if (ov > bv || (ov == bv && oa < ba)) { bv = ov; ba = oa; }
        }
        if (lane == 0) { s_rv[wv] = bv; s_ra[wv] = ba; }
        __syncthreads();
        if (tid == 0) {
            for (int w = 1; w < 4; w++) {
                if (s_rv[w] > bv || (s_rv[w] == bv && s_ra[w] < ba)) { bv = s_rv[w]; ba = s_ra[w]; }
            }
            if (bv > 1e-9f) {
                s_win = ba;
                size_t t = (size_t)b * NA + ba;
                atomicOr(&bits[t * 4 + (g >> 5)], 1u << (g & 31));
                unsigned int old = atomicAdd(&selcnt[t], 1u);
                if (old >= 1u) atomicOr(flag, 1);
            } else {
                s_win = 0xFFFFFFFFu;
            }
        }
        __syncthreads();
        unsigned int win = s_win;
        if (win == 0xFFFFFFFFu) break;
        for (int i = tid; i < qn; i += 256) {
            if (s_idx[i] == (unsigned short)win) s_val[i] = -1.0f;
        }
        __syncthreads();
    }
}

// K2: per-anchor resolution + all 5 outputs (align/iou recomputed only at set bits)
__global__ __launch_bounds__(256) void k_final(
    const float* __restrict__ scores, const float* __restrict__ pboxes,
    const int* __restrict__ glab, const float* __restrict__ gboxes,
    const float* __restrict__ gmask,
    const unsigned int* __restrict__ bits, const int* __restrict__ flagp,
    const unsigned long long* __restrict__ bestkey,
    float* __restrict__ o_cls, float* __restrict__ o_bbox, float* __restrict__ o_scores,
    float* __restrict__ o_mask, float* __restrict__ o_norm)
{
    __shared__ float4 s_gb[NG];
    __shared__ int s_gl[NG];
    __shared__ float s_gm[NG];
    int b = blockIdx.y;
    for (int i = threadIdx.x; i < NG; i += 256) {
        s_gb[i] = ((const float4*)gboxes)[b * NG + i];
        s_gl[i] = glab[b * NG + i];
        s_gm[i] = gmask[b * NG + i];
    }
    __syncthreads();
    int a = blockIdx.x * 256 + threadIdx.x;
    if (a >= NA) return;
    size_t t = (size_t)b * NA + a;
    unsigned int ew[4];
    ew[0] = bits[t * 4 + 0]; ew[1] = bits[t * 4 + 1];
    ew[2] = bits[t * 4 + 2]; ew[3] = bits[t * 4 + 3];
    int cnt = __popc(ew[0]) + __popc(ew[1]) + __popc(ew[2]) + __popc(ew[3]);
    bool conflict_any = (flagp[0] != 0);
    unsigned long long key = bestkey[t];
    float best_v = __uint_as_float((unsigned int)(key >> 32));
    int best_g = 127 - (int)(key & 0x7Fu);
    float4 pb = ((const float4*)pboxes)[t];
    const float* srow = scores + t * NC;

    bool keep = (cnt <= 1);
    float M = 0.0f, mxiou = 0.0f;
    int tgt = 0;
    float fmask = 0.0f;

    if (!conflict_any) {
        fmask = (cnt > 0) ? 1.0f : 0.0f;
        for (int w = 0; w < 4; w++) {
            if (ew[w]) { tgt = w * 32 + __ffs(ew[w]) - 1; break; }
        }
        for (int w = 0; w < 4; w++) {
            unsigned int m = ew[w];
            while (m) {
                int j = __ffs(m) - 1; m &= m - 1;
                int g = w * 32 + j;
                float4 gb = s_gb[g];
                float iv = dev_ciou(pb.x, pb.y, pb.z, pb.w, gb.x, gb.y, gb.z, gb.w);
                float s = srow[s_gl[g]];
                float av = (s * powf(iv, 6.0f)) * s_gm[g];   // bit-identical to build
                M = fmaxf(M, av);
                mxiou = fmaxf(mxiou, iv);
            }
        }
    } else if (!keep) {
        fmask = 0.0f; tgt = 0; M = 0.0f; mxiou = 0.0f;   // resolved row all zero
    } else {
        fmask = 1.0f;   // one_hot_best always contributes
        bool eff_best = ((ew[best_g >> 5] >> (best_g & 31)) & 1u) != 0u;
        int first_eff = 1 << 30;
        for (int w = 0; w < 4; w++) {
            if (ew[w]) { first_eff = w * 32 + __ffs(ew[w]) - 1; break; }
        }
        tgt = eff_best ? best_g : (first_eff < best_g ? first_eff : best_g);
        for (int w = 0; w < 4; w++) {
            unsigned int m = ew[w];
            while (m) {
                int j = __ffs(m) - 1; m &= m - 1;
                int g = w * 32 + j;
                float r = (g == best_g) ? 2.0f : 1.0f;
                float4 gb = s_gb[g];
                float iv = dev_ciou(pb.x, pb.y, pb.z, pb.w, gb.x, gb.y, gb.z, gb.w);
                float s = srow[s_gl[g]];
                float av = (s * powf(iv, 6.0f)) * s_gm[g];
                M = fmaxf(M, av * r);
                mxiou = fmaxf(mxiou, iv * r);
            }
        }
        if (!eff_best) {   // one_hot_best adds weight 1 at best_g
            float4 gb = s_gb[best_g];
            float iv = dev_ciou(pb.x, pb.y, pb.z, pb.w, gb.x, gb.y, gb.z, gb.w);
            M = fmaxf(M, best_v);
            mxiou = fmaxf(mxiou, iv);
        }
    }

    float norm = (M * M) / (mxiou + 1e-9f);
    int cls = s_gl[tgt];
    float4 gb = s_gb[tgt];
    o_cls[t] = (float)cls;
    ((float4*)o_bbox)[t] = gb;
    o_mask[t] = fmask;
    o_norm[t] = norm;
    float* orow = o_scores + t * (size_t)NC;
    #pragma unroll
    for (int j = 0; j < NC / 4; j++) {
        int base = j * 4;
        float4 z;
        z.x = (cls == base + 0) ? norm : 0.0f;
        z.y = (cls == base + 1) ? norm : 0.0f;
        z.z = (cls == base + 2) ? norm : 0.0f;
        z.w = (cls == base + 3) ? norm : 0.0f;
        ((float4*)orow)[j] = z;
    }
}

extern "C" void kernel_launch(void* const* d_in, const int* in_sizes, int n_in,
                              void* d_out, int out_size, void* d_ws, size_t ws_size,
                              hipStream_t stream) {
    const float* pd_scores = (const float*)d_in[0];
    const float* pd_bboxes = (const float*)d_in[1];
    const float* anc       = (const float*)d_in[2];
    const int*   glab      = (const int*)d_in[3];
    const float* gboxes    = (const float*)d_in[4];
    const float* gmask     = (const float*)d_in[5];
    float* out = (float*)d_out;

    char* ws = (char*)d_ws;
    unsigned int*       bits    = (unsigned int*)(ws + OFF_BITS);
    unsigned int*       selcnt  = (unsigned int*)(ws + OFF_SELCNT);
    int*                flag    = (int*)(ws + OFF_FLAG);
    unsigned long long* bestkey = (unsigned long long*)(ws + OFF_BESTK);

    k_init<<<(BS * NA + 255) / 256, 256, 0, stream>>>(bits, selcnt, flag, bestkey);

    k_build_select<<<dim3(NG, BS), 256, 0, stream>>>(
        pd_scores, pd_bboxes, anc, glab, gboxes, gmask, bits, selcnt, flag, bestkey);

    k_final<<<dim3((NA + 255) / 256, BS), 256, 0, stream>>>(
        pd_scores, pd_bboxes, glab, gboxes, gmask, bits, flag, bestkey,
        out + OUT_CLS, out + OUT_BBOX, out + OUT_SCORES, out + OUT_MASK, out + OUT_NORM);
}

// Round 5
// 145.703 us; speedup vs baseline: 1.0167x; 1.0167x over previous
//
#include <hip/hip_runtime.h>
#include <math.h>

#pragma clang fp contract(off)

#define BS 16
#define NA 8400
#define NG 128
#define NC 80
#define KTOP 13
#define QCAP 1024   // per-column in-box queue capacity (worst case ~500)
#define NCH (QCAP / 64)

// ---- workspace layout (bytes) ----
#define OFF_BITS   0                                    // BS*NA*4 u32 = 2,150,400
#define OFF_SELCNT ((size_t)BS * NA * 16)               // BS*NA u32   =   537,600
#define OFF_FLAG   (OFF_SELCNT + (size_t)BS * NA * 4)   // 256 bytes
#define OFF_BESTK  (OFF_FLAG + 256)                     // BS*NA u64   = 1,075,200

// ---- output layout (float elements) ----
#define OUT_CLS    0
#define OUT_BBOX   (BS * NA)
#define OUT_SCORES (OUT_BBOX + BS * NA * 4)
#define OUT_MASK   (OUT_SCORES + BS * NA * NC)
#define OUT_NORM   (OUT_MASK + BS * NA)

__device__ __forceinline__ float dev_ciou(float px1, float py1, float px2, float py2,
                                          float gx1, float gy1, float gx2, float gy2) {
    const float eps = 1e-7f;
    float iw = fminf(px2, gx2) - fmaxf(px1, gx1); iw = fmaxf(iw, 0.0f);
    float ih = fminf(py2, gy2) - fmaxf(py1, gy1); ih = fmaxf(ih, 0.0f);
    float inter = iw * ih;
    float w1 = px2 - px1;
    float h1 = (py2 - py1) + eps;
    float w2 = gx2 - gx1;
    float h2 = (gy2 - gy1) + eps;
    float uni = ((w1 * h1 + w2 * h2) - inter) + eps;
    float iou = inter / uni;
    float cw = fmaxf(px2, gx2) - fminf(px1, gx1);
    float ch = fmaxf(py2, gy2) - fminf(py1, gy1);
    float c2 = (cw * cw + ch * ch) + eps;
    float tx = ((gx1 + gx2) - px1) - px2;
    float ty = ((gy1 + gy2) - py1) - py2;
    float rho2 = (tx * tx + ty * ty) / 4.0f;
    float da = atanf(w2 / h2) - atanf(w1 / h1);
    float v = ((float)(4.0 / (M_PI * M_PI))) * (da * da);
    float alpha = v / ((v - iou) + (float)(1.0 + 1e-7));
    float res = iou - (rho2 / c2 + v * alpha);
    return fmaxf(res, 0.0f);
}

// K0: zero bits/selcnt/flag, seed bestkey = pack(al=0.0f, g=0) = 127
__global__ __launch_bounds__(256) void k_init(
    unsigned int* __restrict__ bits, unsigned int* __restrict__ selcnt,
    int* __restrict__ flag, unsigned long long* __restrict__ bestkey)
{
    int i = blockIdx.x * 256 + threadIdx.x;
    if (i < BS * NA) {
        ((uint4*)bits)[i] = make_uint4(0u, 0u, 0u, 0u);
        selcnt[i] = 0u;
        bestkey[i] = 127ULL;
    }
    if (i == 0) *flag = 0;
}

// K1: fused build+select, one block per (b,g) column.
// Phase 1 (256 thr): cheap in-box scan -> LDS queue of anchor ids.
// Phase 2 (256 thr): dense align over the queue; global atomicMax best key.
// Phase 3 (WAVE 0 ONLY, registers, no barriers): top-13 value-desc/anchor-asc,
//          early break when max <= 1e-9; scatter bits + selcnt + flag.
__global__ __launch_bounds__(256) void k_build_select(
    const float* __restrict__ scores, const float* __restrict__ pboxes,
    const float* __restrict__ anc, const int* __restrict__ glab,
    const float* __restrict__ gboxes, const float* __restrict__ gmask,
    unsigned int* __restrict__ bits, unsigned int* __restrict__ selcnt,
    int* __restrict__ flag, unsigned long long* __restrict__ bestkey)
{
    __shared__ unsigned short s_idx[QCAP];
    __shared__ float s_val[QCAP];
    __shared__ unsigned int s_qn;

    int g = blockIdx.x, b = blockIdx.y;
    int col = b * NG + g;
    int tid = threadIdx.x;
    float gm = gmask[col];                 // block-uniform
    float gx1 = gboxes[col * 4 + 0], gy1 = gboxes[col * 4 + 1];
    float gx2 = gboxes[col * 4 + 2], gy2 = gboxes[col * 4 + 3];
    int cls = glab[col];
    if (tid == 0) s_qn = 0;
    __syncthreads();

    // phase 1: cheap in-box scan
    if (gm != 0.0f) {
        for (int a = tid; a < NA; a += 256) {
            float2 ap = ((const float2*)anc)[a];
            float mn = fminf(fminf(ap.x - gx1, ap.y - gy1), fminf(gx2 - ap.x, gy2 - ap.y));
            if (mn > 1e-9f) {
                unsigned int pos = atomicAdd(&s_qn, 1u);
                if (pos < QCAP) s_idx[pos] = (unsigned short)a;
            }
        }
    }
    __syncthreads();
    int qn = (int)s_qn; if (qn > QCAP) qn = QCAP;

    // phase 2: dense align over the queue
    for (int i = tid; i < qn; i += 256) {
        int a = (int)s_idx[i];
        size_t t = (size_t)b * NA + a;
        float4 pb = ((const float4*)pboxes)[t];
        float iou = dev_ciou(pb.x, pb.y, pb.z, pb.w, gx1, gy1, gx2, gy2);
        float s = scores[t * NC + cls];
        float al = (s * powf(iou, 6.0f)) * gm;   // same expr as reference path
        s_val[i] = (al > 1e-9f) ? al : -1.0f;    // sentinel: excluded from top-k
        // first-occurrence row argmax: al>=0 -> bits order-monotone; (127-g)
        // low bits make smaller g win ties under max.
        unsigned long long key =
            ((unsigned long long)__float_as_uint(al) << 32) | (unsigned int)(127 - g);
        atomicMax(&bestkey[t], key);
    }
    __syncthreads();

    // phase 3: wave 0 only, fully in-register, no barriers
    if (!(gm > 0.0f)) return;   // column excluded from is_in (uniform)
    if (tid >= 64) return;      // waves 1..3 retire
    int lane = tid;
    float v[NCH]; unsigned int ai[NCH];
    int nch = (qn + 63) >> 6;
    #pragma unroll
    for (int j = 0; j < NCH; j++) {
        int i = j * 64 + lane;
        if (i < qn) { v[j] = s_val[i]; ai[j] = (unsigned int)s_idx[i]; }
        else        { v[j] = -1.0f;    ai[j] = 0xFFFFFFFFu; }
    }
    for (int k = 0; k < KTOP; k++) {
        float bv = -1.0f; unsigned int ba = 0xFFFFFFFFu;
        #pragma unroll
        for (int j = 0; j < NCH; j++) {
            if (j < nch) {
                if (v[j] > bv || (v[j] == bv && ai[j] < ba)) { bv = v[j]; ba = ai[j]; }
            }
        }
        for (int off = 1; off < 64; off <<= 1) {
            float ov = __shfl_xor(bv, off);
            unsigned int oa = (unsigned int)__shfl_xor((int)ba, off);
            if (ov > bv || (ov == bv && oa < ba)) { bv = ov; ba = oa; }
        }
        if (!(bv > 1e-9f)) break;   // uniform after butterfly; rest would be filtered
        #pragma unroll
        for (int j = 0; j < NCH; j++) {
            if (ai[j] == ba) v[j] = -1.0f;   // anchors unique within a column
        }
        if (lane == 0) {
            size_t t = (size_t)b * NA + ba;
            atomicOr(&bits[t * 4 + (g >> 5)], 1u << (g & 31));
            unsigned int old = atomicAdd(&selcnt[t], 1u);
            if (old >= 1u) atomicOr(flag, 1);
        }
    }
}

// K2: per-anchor resolution + all 5 outputs (align/iou recomputed only at set bits)
__global__ __launch_bounds__(256) void k_final(
    const float* __restrict__ scores, const float* __restrict__ pboxes,
    const int* __restrict__ glab, const float* __restrict__ gboxes,
    const float* __restrict__ gmask,
    const unsigned int* __restrict__ bits, const int* __restrict__ flagp,
    const unsigned long long* __restrict__ bestkey,
    float* __restrict__ o_cls, float* __restrict__ o_bbox, float* __restrict__ o_scores,
    float* __restrict__ o_mask, float* __restrict__ o_norm)
{
    __shared__ float4 s_gb[NG];
    __shared__ int s_gl[NG];
    __shared__ float s_gm[NG];
    int b = blockIdx.y;
    for (int i = threadIdx.x; i < NG; i += 256) {
        s_gb[i] = ((const float4*)gboxes)[b * NG + i];
        s_gl[i] = glab[b * NG + i];
        s_gm[i] = gmask[b * NG + i];
    }
    __syncthreads();
    int a = blockIdx.x * 256 + threadIdx.x;
    if (a >= NA) return;
    size_t t = (size_t)b * NA + a;
    unsigned int ew[4];
    ew[0] = bits[t * 4 + 0]; ew[1] = bits[t * 4 + 1];
    ew[2] = bits[t * 4 + 2]; ew[3] = bits[t * 4 + 3];
    int cnt = __popc(ew[0]) + __popc(ew[1]) + __popc(ew[2]) + __popc(ew[3]);
    bool conflict_any = (flagp[0] != 0);
    unsigned long long key = bestkey[t];
    float best_v = __uint_as_float((unsigned int)(key >> 32));
    int best_g = 127 - (int)(key & 0x7Fu);
    float4 pb = ((const float4*)pboxes)[t];
    const float* srow = scores + t * NC;

    bool keep = (cnt <= 1);
    float M = 0.0f, mxiou = 0.0f;
    int tgt = 0;
    float fmask = 0.0f;

    if (!conflict_any) {
        fmask = (cnt > 0) ? 1.0f : 0.0f;
        for (int w = 0; w < 4; w++) {
            if (ew[w]) { tgt = w * 32 + __ffs(ew[w]) - 1; break; }
        }
        for (int w = 0; w < 4; w++) {
            unsigned int m = ew[w];
            while (m) {
                int j = __ffs(m) - 1; m &= m - 1;
                int g = w * 32 + j;
                float4 gb = s_gb[g];
                float iv = dev_ciou(pb.x, pb.y, pb.z, pb.w, gb.x, gb.y, gb.z, gb.w);
                float s = srow[s_gl[g]];
                float av = (s * powf(iv, 6.0f)) * s_gm[g];   // bit-identical to build
                M = fmaxf(M, av);
                mxiou = fmaxf(mxiou, iv);
            }
        }
    } else if (!keep) {
        fmask = 0.0f; tgt = 0; M = 0.0f; mxiou = 0.0f;   // resolved row all zero
    } else {
        fmask = 1.0f;   // one_hot_best always contributes
        bool eff_best = ((ew[best_g >> 5] >> (best_g & 31)) & 1u) != 0u;
        int first_eff = 1 << 30;
        for (int w = 0; w < 4; w++) {
            if (ew[w]) { first_eff = w * 32 + __ffs(ew[w]) - 1; break; }
        }
        tgt = eff_best ? best_g : (first_eff < best_g ? first_eff : best_g);
        for (int w = 0; w < 4; w++) {
            unsigned int m = ew[w];
            while (m) {
                int j = __ffs(m) - 1; m &= m - 1;
                int g = w * 32 + j;
                float r = (g == best_g) ? 2.0f : 1.0f;
                float4 gb = s_gb[g];
                float iv = dev_ciou(pb.x, pb.y, pb.z, pb.w, gb.x, gb.y, gb.z, gb.w);
                float s = srow[s_gl[g]];
                float av = (s * powf(iv, 6.0f)) * s_gm[g];
                M = fmaxf(M, av * r);
                mxiou = fmaxf(mxiou, iv * r);
            }
        }
        if (!eff_best) {   // one_hot_best adds weight 1 at best_g
            float4 gb = s_gb[best_g];
            float iv = dev_ciou(pb.x, pb.y, pb.z, pb.w, gb.x, gb.y, gb.z, gb.w);
            M = fmaxf(M, best_v);
            mxiou = fmaxf(mxiou, iv);
        }
    }

    float norm = (M * M) / (mxiou + 1e-9f);
    int cls = s_gl[tgt];
    float4 gb = s_gb[tgt];
    o_cls[t] = (float)cls;
    ((float4*)o_bbox)[t] = gb;
    o_mask[t] = fmask;
    o_norm[t] = norm;
    float* orow = o_scores + t * (size_t)NC;
    #pragma unroll
    for (int j = 0; j < NC / 4; j++) {
        int base = j * 4;
        float4 z;
        z.x = (cls == base + 0) ? norm : 0.0f;
        z.y = (cls == base + 1) ? norm : 0.0f;
        z.z = (cls == base + 2) ? norm : 0.0f;
        z.w = (cls == base + 3) ? norm : 0.0f;
        ((float4*)orow)[j] = z;
    }
}

extern "C" void kernel_launch(void* const* d_in, const int* in_sizes, int n_in,
                              void* d_out, int out_size, void* d_ws, size_t ws_size,
                              hipStream_t stream) {
    const float* pd_scores = (const float*)d_in[0];
    const float* pd_bboxes = (const float*)d_in[1];
    const float* anc       = (const float*)d_in[2];
    const int*   glab      = (const int*)d_in[3];
    const float* gboxes    = (const float*)d_in[4];
    const float* gmask     = (const float*)d_in[5];
    float* out = (float*)d_out;

    char* ws = (char*)d_ws;
    unsigned int*       bits    = (unsigned int*)(ws + OFF_BITS);
    unsigned int*       selcnt  = (unsigned int*)(ws + OFF_SELCNT);
    int*                flag    = (int*)(ws + OFF_FLAG);
    unsigned long long* bestkey = (unsigned long long*)(ws + OFF_BESTK);

    k_init<<<(BS * NA + 255) / 256, 256, 0, stream>>>(bits, selcnt, flag, bestkey);

    k_build_select<<<dim3(NG, BS), 256, 0, stream>>>(
        pd_scores, pd_bboxes, anc, glab, gboxes, gmask, bits, selcnt, flag, bestkey);

    k_final<<<dim3((NA + 255) / 256, BS), 256, 0, stream>>>(
        pd_scores, pd_bboxes, glab, gboxes, gmask, bits, flag, bestkey,
        out + OUT_CLS, out + OUT_BBOX, out + OUT_SCORES, out + OUT_MASK, out + OUT_NORM);
}